// Round 1
// baseline (223.451 us; speedup 1.0000x reference)
//
#include <hip/hip_runtime.h>
#include <cstdint>
#include <cstddef>

// Problem constants (fixed by the reference)
#define B_      32
#define N_      8400
#define C_      80
#define NC      672000        // N_*C_
#define NCV4    168000        // NC/4
#define NBINS   4096
#define TOPK    1024
#define MAXDET  300
#define CANDCAP 4096
#define NSLICE  16
#define SLICE_V4 10500        // NCV4 / NSLICE
#define NBKT    8             // score bins 4088..4095 (all x in [0.998..1))
#define SEGB    64            // per-(batch,bucket,slice) cap (mean 10.25, 17 sigma)
#define BSORT   256           // per-bucket cap (mean 164, 7.2 sigma)
#define CLS_CAP 128           // per-class NMS cap (mean 12.8, 32 sigma)

// Static stage threshold: score >= 4088/4096 = 0.998046875.
// Expected candidates/batch = 672000*8/4096 = 1312 (sd ~36). Bucket = bin-4088
// partitions candidates into 8 ORDER-DISJOINT groups (floor is monotone, float
// bits are monotone): buckets concatenated 7..0 == exact lax.top_k order
// (score desc, index asc via key low bits). Violating inputs take the exact
// in-kernel histogram fallback (never on bench input).
#define STAGE_THRESH 0.998046875f

// Workspace layout (bytes) — only staging buffers remain in global memory.
#define WS_SEGKEYS  0           // 32*8*16*64*8 = 2097152
#define WS_SEGCNT   2097152     // 32*8*16*4    = 16384

// Output layout (float32, concatenated): boxes[32][300][4], scores[32][300],
// labels[32][300], n_valid[32]
#define OUT_SCORES  38400
#define OUT_LABELS  48000
#define OUT_NVALID  57600

// ---------------------------------------------------------------------------
// K1: single-pass filter+stage into PRIVATE per-(batch,bucket,slice) segments.
// key = (bits(v)<<32) | ~flat_idx. 8 LDS counters per block; plain global
// stores; no global atomics, no pre-zeroing (raw counts let K2 detect
// overflow -> fallback). Memory-bound: 86 MB read ~= 15 us; unchanged.
__global__ __launch_bounds__(256) void stage_kernel(const float4* __restrict__ scores4,
                                                    unsigned* __restrict__ segCnt,
                                                    unsigned long long* __restrict__ segKeys) {
    __shared__ unsigned lcnt[NBKT];
    int b = blockIdx.x, sl = blockIdx.y, tid = threadIdx.x;
    if (tid < NBKT) lcnt[tid] = 0;
    __syncthreads();
    const float4* s = scores4 + (size_t)b * NCV4 + (size_t)sl * SLICE_V4;
    for (int i = tid; i < SLICE_V4; i += 256) {
        float4 v = s[i];
        float c[4] = {v.x, v.y, v.z, v.w};
        unsigned flat0 = ((unsigned)sl * SLICE_V4 + (unsigned)i) * 4u;
        #pragma unroll
        for (int kc = 0; kc < 4; ++kc) {
            float x = (c[kc] > 0.001f) ? c[kc] : 0.0f;
            if (x >= STAGE_THRESH) {
                int bin = (int)(x * 4096.0f);             // exact: x * 2^12
                bin = bin > (NBINS - 1) ? (NBINS - 1) : bin;
                int bkt = bin - 4088;                      // 0..7
                unsigned p = atomicAdd(&lcnt[bkt], 1u);
                if (p < (unsigned)SEGB)
                    segKeys[(((size_t)(b * NBKT + bkt)) * NSLICE + sl) * SEGB + p] =
                        ((unsigned long long)__float_as_uint(x) << 32) |
                        (unsigned long long)(0xFFFFFFFFu - (flat0 + kc));
            }
        }
    }
    __syncthreads();
    if (tid < NBKT) segCnt[(b * NBKT + tid) * NSLICE + sl] = lcnt[tid];
}

// ---------------------------------------------------------------------------
// K2 (fused): per batch, ONE 1024-thread block does select+rank, NMS, and
// finalize, all intermediates in LDS (~86 KB). Replaces the old sortb (36-pass
// bitonic = 36 dependent LDS round-trips at 1 wave/CU), nms (2560 blocks
// re-scanning the list from global across non-coherent XCD L2s), and finalize
// (a 4th launch). Rank-and-scatter: within an order-disjoint bucket, final
// position = bucket base + #{greater keys} — pure broadcast-compare VALU,
// no sort network, no fences. NMS: 16 waves x 5 classes, barrier-free in-wave
// greedy (lockstep + threadfence_block, same discipline as the old bitonic).
__global__ __launch_bounds__(1024) void fused_kernel(
        const float4* __restrict__ scores4,
        const unsigned long long* __restrict__ segKeys,
        const unsigned* __restrict__ segCnt,
        const float4* __restrict__ boxes4,
        float* __restrict__ out) {
    __shared__ unsigned scnt2[NBKT][NSLICE];   // 512 B
    __shared__ unsigned bsum[NBKT];
    __shared__ unsigned bok[NBKT];
    __shared__ unsigned spref[NBKT][NSLICE];   // per-bucket slice prefix
    __shared__ float   sScore[TOPK];           // 4 KB
    __shared__ int     sCls[TOPK];             // 4 KB
    __shared__ int     sBoxIdx[TOPK];          // 4 KB
    __shared__ float4  sBox[TOPK];             // 16 KB
    __shared__ int     sKeep[TOPK];            // 4 KB
    __shared__ int     sk[TOPK];               // 4 KB (scan)
    __shared__ int     sel[MAXDET];            // 1.2 KB
    __shared__ int     s_cut;
    __shared__ unsigned s_scnt;
    // union pool: fast path NMS scratch (47 KB) vs fallback kbuf+hist (48 KB).
    // kbuf/fh are dead before any NMS-scratch write (syncthreads separated).
    __shared__ __align__(16) char upool[49152];
    unsigned long long* kbuf = (unsigned long long*)upool;          // [4096] 32 KB
    unsigned* fh = (unsigned*)(upool + 32768);                      // [4096] 16 KB
    float* ny1 = (float*)upool;                                     // [16*128]
    float* nx1 = ny1 + 16 * CLS_CAP;
    float* ny2 = nx1 + 16 * CLS_CAP;
    float* nx2 = ny2 + 16 * CLS_CAP;
    float* nar = nx2 + 16 * CLS_CAP;                                // @32768
    unsigned short* npos = (unsigned short*)(nar + 16 * CLS_CAP);   // @40960
    unsigned char*  nsup = (unsigned char*)(npos + 16 * CLS_CAP);   // @45056

    int b = blockIdx.x;
    int tid = threadIdx.x;
    int lane = tid & 63;
    int wave = tid >> 6;

    // ---- P0: load per-segment counts; bucket sums, validity, slice prefixes.
    if (tid < NBKT * NSLICE)
        scnt2[tid >> 4][tid & 15] = segCnt[b * NBKT * NSLICE + tid];
    __syncthreads();
    if (tid < NBKT) {
        unsigned ssum = 0, ok = 1;
        #pragma unroll
        for (int sl = 0; sl < NSLICE; ++sl) {
            unsigned v = scnt2[tid][sl];
            if (v > (unsigned)SEGB) ok = 0;
            ssum += v;
        }
        bsum[tid] = ssum; bok[tid] = ok;
    }
    if (tid < NBKT * NSLICE) {
        int bkt = tid >> 4, sl = tid & 15;
        unsigned acc = 0;
        for (int s2 = 0; s2 < sl; ++s2) acc += scnt2[bkt][s2];
        spref[bkt][sl] = acc;
    }
    __syncthreads();
    unsigned M = 0; int valid = 1;
    #pragma unroll
    for (int t = 0; t < NBKT; ++t) {
        unsigned s2 = bsum[t];
        if (!bok[t] || s2 > (unsigned)BSORT) valid = 0;
        M += s2;
    }
    if (M < (unsigned)TOPK || M > (unsigned)CANDCAP) valid = 0;
    // `valid` is uniform across the block (computed from identical LDS data).

    if (valid) {
        // ---- P1: gather segments into per-bucket contiguous kbuf regions.
        for (int seg = wave; seg < NBKT * NSLICE; seg += 16) {
            int bkt = seg >> 4, sl = seg & 15;
            unsigned c2 = scnt2[bkt][sl];            // <= SEGB in valid path
            const unsigned long long* src =
                segKeys + (((size_t)(b * NBKT + bkt)) * NSLICE + sl) * SEGB;
            if ((unsigned)lane < c2)
                kbuf[bkt * BSORT + spref[bkt][sl] + lane] = src[lane];
        }
        __syncthreads();
        // ---- P2: rank within bucket (desc) & scatter to final position.
        // 128 threads per bucket, 2 keys each; inner loop is LDS broadcast.
        int bkt = tid >> 7;
        unsigned n = bsum[bkt];
        unsigned base = 0;
        for (int t = bkt + 1; t < NBKT; ++t) base += bsum[t];
        if (base < (unsigned)TOPK && n > 0) {
            const unsigned long long* kb = kbuf + bkt * BSORT;
            int j0 = tid & 127, j1 = j0 + 128;
            unsigned long long k0 = (j0 < (int)n) ? kb[j0] : 0ull;
            unsigned long long k1 = (j1 < (int)n) ? kb[j1] : 0ull;
            unsigned r0 = 0, r1 = 0;
            for (unsigned i = 0; i < n; ++i) {
                unsigned long long ki = kb[i];
                r0 += (ki > k0); r1 += (ki > k1);
            }
            if (j0 < (int)n) {
                unsigned pos = base + r0;
                if (pos < (unsigned)TOPK) {
                    unsigned idx = 0xFFFFFFFFu - (unsigned)(k0 & 0xFFFFFFFFull);
                    if (idx >= (unsigned)NC) idx = 0;   // defensive
                    unsigned bi = idx / (unsigned)C_;
                    sScore[pos] = __uint_as_float((unsigned)(k0 >> 32));
                    sCls[pos] = (int)(idx - bi * (unsigned)C_);
                    sBoxIdx[pos] = (int)bi;
                }
            }
            if (j1 < (int)n) {
                unsigned pos = base + r1;
                if (pos < (unsigned)TOPK) {
                    unsigned idx = 0xFFFFFFFFu - (unsigned)(k1 & 0xFFFFFFFFull);
                    if (idx >= (unsigned)NC) idx = 0;
                    unsigned bi = idx / (unsigned)C_;
                    sScore[pos] = __uint_as_float((unsigned)(k1 >> 32));
                    sCls[pos] = (int)(idx - bi * (unsigned)C_);
                    sBoxIdx[pos] = (int)bi;
                }
            }
        }
    } else {
        // ---- exact fallback (never on bench input): histogram cut + bitonic.
        for (int i = tid; i < NBINS; i += 1024) fh[i] = 0;
        if (tid == 0) s_scnt = 0;
        __syncthreads();
        const float4* s = scores4 + (size_t)b * NCV4;
        for (int i = tid; i < NCV4; i += 1024) {
            float4 v = s[i];
            float c4[4] = {v.x, v.y, v.z, v.w};
            #pragma unroll
            for (int kc = 0; kc < 4; ++kc) {
                float x = (c4[kc] > 0.001f) ? c4[kc] : 0.0f;
                int bin = (int)(x * 4096.0f);
                bin = bin > (NBINS - 1) ? (NBINS - 1) : bin;
                atomicAdd(&fh[bin], 1u);
            }
        }
        __syncthreads();
        if (tid == 0) {
            unsigned acc = 0; int cb2 = 0;
            for (int bin = NBINS - 1; bin >= 0; --bin) {
                acc += fh[bin];
                if (acc >= (unsigned)TOPK) { cb2 = bin; break; }
            }
            s_cut = cb2;
        }
        __syncthreads();
        int cb = s_cut;
        for (int i = tid; i < NCV4; i += 1024) {
            float4 v = s[i];
            float c4[4] = {v.x, v.y, v.z, v.w};
            unsigned flat0 = (unsigned)i * 4u;
            #pragma unroll
            for (int kc = 0; kc < 4; ++kc) {
                float x = (c4[kc] > 0.001f) ? c4[kc] : 0.0f;
                int bin = (int)(x * 4096.0f);
                bin = bin > (NBINS - 1) ? (NBINS - 1) : bin;
                if (bin >= cb) {
                    unsigned p = atomicAdd(&s_scnt, 1u);
                    if (p < (unsigned)CANDCAP)
                        kbuf[p] = ((unsigned long long)__float_as_uint(x) << 32) |
                                  (unsigned long long)(0xFFFFFFFFu - (flat0 + kc));
                }
            }
        }
        __syncthreads();
        unsigned M2 = s_scnt; if (M2 > (unsigned)CANDCAP) M2 = CANDCAP;
        int S = (M2 <= 1024u) ? 1024 : (M2 <= 2048u ? 2048 : CANDCAP);
        for (int i = (int)M2 + tid; i < S; i += 1024) kbuf[i] = 0ull;
        __syncthreads();
        for (int kk = 2; kk <= S; kk <<= 1) {
            for (int j = kk >> 1; j > 0; j >>= 1) {
                for (int t = tid; t < S; t += 1024) {
                    int l = t ^ j;
                    if (l > t) {
                        unsigned long long a0 = kbuf[t], c0 = kbuf[l];
                        bool sw = ((t & kk) == 0) ? (a0 < c0) : (a0 > c0);
                        if (sw) { kbuf[t] = c0; kbuf[l] = a0; }
                    }
                }
                __syncthreads();
            }
        }
        for (int r = tid; r < TOPK; r += 1024) {
            unsigned long long key = kbuf[r];
            unsigned idx = 0xFFFFFFFFu - (unsigned)(key & 0xFFFFFFFFull);
            if (idx >= (unsigned)NC) idx = 0;
            unsigned bi = idx / (unsigned)C_;
            sScore[r] = __uint_as_float((unsigned)(key >> 32));
            sCls[r] = (int)(idx - bi * (unsigned)C_);
            sBoxIdx[r] = (int)bi;
        }
    }
    __syncthreads();

    // ---- P3: gather boxes (L2/L3-resident, 16 KB/batch), init keep.
    {
        int bi = sBoxIdx[tid];
        sKeep[tid] = 0;
        sBox[tid] = boxes4[(size_t)b * N_ + bi];
    }
    __syncthreads();

    // ---- P5: per-class greedy NMS; wave w owns classes w, w+16, ... (5 each).
    // Cross-class IoU is exactly 0 (offset gap 4096 >> max box 640), so
    // per-class greedy == reference's global sequential loop. IoU replicated
    // in f32 with __fmul_rn to block FMA contraction. Single-wave lockstep,
    // no block barriers inside (waves diverge); LDS ordered by threadfence.
    for (int c = wave; c < C_; c += 16) {
        float off = (float)c * 4096.0f;         // exact
        int base2 = 0;
        for (int chunkS = 0; chunkS < TOPK; chunkS += 64) {
            int i = chunkS + lane;
            int cls = sCls[i];
            float sc = sScore[i];
            bool listed = (cls == c) && (sc > 0.001f);
            unsigned long long mask = __ballot(listed);
            int rank = __popcll(mask & ((1ull << lane) - 1ull));
            if (listed) {
                int slot = base2 + rank;
                if (slot < CLS_CAP) {
                    int s5 = wave * CLS_CAP + slot;
                    float4 tb = sBox[i];
                    float y1 = tb.x + off, x1 = tb.y + off;
                    float y2 = tb.z + off, x2 = tb.w + off;
                    npos[s5] = (unsigned short)i;
                    ny1[s5] = y1; nx1[s5] = x1; ny2[s5] = y2; nx2[s5] = x2;
                    nar[s5] = __fmul_rn((x2 - x1) + 1.0f, (y2 - y1) + 1.0f);
                    nsup[s5] = 0;
                }
            }
            base2 += __popcll(mask);
        }
        int m = base2 < CLS_CAP ? base2 : CLS_CAP;
        __threadfence_block();                   // extraction visible in-wave
        int cur = 0;
        while (cur < m) {
            int sc5 = wave * CLS_CAP + cur;
            if (lane == 0) sKeep[npos[sc5]] = 1;
            float cy1 = ny1[sc5], cx1 = nx1[sc5], cy2 = ny2[sc5], cx2 = nx2[sc5];
            float carea = nar[sc5];
            for (int j = cur + 1 + lane; j < m; j += 64) {
                int t5 = wave * CLS_CAP + j;
                if (!nsup[t5]) {
                    float yy1 = fmaxf(cy1, ny1[t5]), xx1 = fmaxf(cx1, nx1[t5]);
                    float yy2 = fminf(cy2, ny2[t5]), xx2 = fminf(cx2, nx2[t5]);
                    float w = fmaxf(0.0f, (xx2 - xx1) + 1.0f);
                    float h = fmaxf(0.0f, (yy2 - yy1) + 1.0f);
                    float inter = __fmul_rn(w, h);
                    float denom = (carea + nar[t5]) - inter;
                    float iou = inter / denom;
                    if (iou > 0.7f) nsup[t5] = 1;
                }
            }
            __threadfence_block();
            int nxt = m;
            for (int j = cur + 1 + lane; j < m; j += 64)
                if (!nsup[wave * CLS_CAP + j]) { nxt = j; break; }
            for (int o = 32; o > 0; o >>= 1) {
                int other = __shfl_xor(nxt, o, 64);
                nxt = nxt < other ? nxt : other;
            }
            cur = nxt;
        }
    }
    __syncthreads();

    // ---- P6: stable top-300 (kept positions in order, then suppressed in
    // order — matches lax.top_k tie-break) + all outputs.
    int kp = sKeep[tid];
    sk[tid] = kp;
    __syncthreads();
    for (int off2 = 1; off2 < TOPK; off2 <<= 1) {
        int add = (tid >= off2) ? sk[tid - off2] : 0;
        __syncthreads();
        sk[tid] += add;
        __syncthreads();
    }
    int nk = sk[TOPK - 1];
    int incl = sk[tid];
    int kexcl = incl - kp;       // exclusive kept rank
    int sexcl = tid - kexcl;     // exclusive suppressed rank
    if (kp) {
        if (kexcl < MAXDET) sel[kexcl] = tid;
    } else {
        int slot = nk + sexcl;
        if (slot < MAXDET) sel[slot] = tid;
    }
    __syncthreads();
    if (tid < MAXDET) {
        int p = sel[tid];
        float sc = (tid < nk) ? sScore[p] : 0.0f;
        float4 tb = sBox[p];
        float* ob = out + ((size_t)b * MAXDET + tid) * 4;
        ob[0] = tb.x; ob[1] = tb.y; ob[2] = tb.z; ob[3] = tb.w;
        out[OUT_SCORES + b * MAXDET + tid] = sc;
        out[OUT_LABELS + b * MAXDET + tid] = (float)sCls[p];
    }
    if (tid == 0) out[OUT_NVALID + b] = (float)(nk < MAXDET ? nk : MAXDET);
}

// ---------------------------------------------------------------------------
extern "C" void kernel_launch(void* const* d_in, const int* in_sizes, int n_in,
                              void* d_out, int out_size, void* d_ws, size_t ws_size,
                              hipStream_t stream) {
    const float* boxes  = (const float*)d_in[0];   // (32, 8400, 4)
    const float* scores = (const float*)d_in[1];   // (32, 8400, 80)
    float* out = (float*)d_out;
    char* ws = (char*)d_ws;

    unsigned long long* segKeys = (unsigned long long*)(ws + WS_SEGKEYS);
    unsigned* segCnt = (unsigned*)(ws + WS_SEGCNT);

    const float4* scores4 = (const float4*)scores;
    const float4* boxes4  = (const float4*)boxes;

    stage_kernel<<<dim3(B_, NSLICE), 256, 0, stream>>>(scores4, segCnt, segKeys);
    fused_kernel<<<B_, 1024, 0, stream>>>(scores4, segKeys, segCnt, boxes4, out);
}

// Round 2
// 179.651 us; speedup vs baseline: 1.2438x; 1.2438x over previous
//
#include <hip/hip_runtime.h>
#include <cstdint>
#include <cstddef>

// Problem constants (fixed by the reference)
#define B_      32
#define N_      8400
#define C_      80
#define NC      672000        // N_*C_
#define NCV4    168000        // NC/4
#define NBINS   4096
#define TOPK    1024
#define MAXDET  300
#define CANDCAP 4096
#define NSLICE  16
#define SLICE_V4 10500        // NCV4 / NSLICE
#define NBKT    8             // score bins 4088..4095 (all x in [0.998..1))
#define SEGB    64            // per-(batch,bucket,slice) cap (mean 10.25, 17 sigma)
#define BSORT   256           // per-bucket cap (mean 164, 7.2 sigma)

// Static stage threshold: score >= 4088/4096 = 0.998046875.
// Expected candidates/batch = 672000*8/4096 = 1312 (sd ~36). Bucket = bin-4088
// partitions candidates into 8 ORDER-DISJOINT groups (floor is monotone, float
// bits are monotone): buckets concatenated 7..0 == exact lax.top_k order
// (score desc, index asc via key low bits). Violating inputs take the exact
// in-kernel histogram fallback (never on bench input).
#define STAGE_THRESH 0.998046875f

// Workspace layout (bytes)
#define WS_SEGKEYS  0           // 32*8*16*64*8 = 2097152
#define WS_SEGCNT   2097152     // 32*8*16*4    = 16384
#define WS_TOPSCORE 2113536     // 32*1024*4    = 131072
#define WS_TOPBOX   2244608     // 32*1024*16   = 524288
#define WS_TOPCLS   2768896     // 32*1024*4    = 131072
#define WS_KEEP     2899968     // 32*1024*4    = 131072

// Output layout (float32, concatenated): boxes[32][300][4], scores[32][300],
// labels[32][300], n_valid[32]
#define OUT_SCORES  38400
#define OUT_LABELS  48000
#define OUT_NVALID  57600

// ---------------------------------------------------------------------------
// K1: single-pass filter+stage into PRIVATE per-(batch,bucket,slice) segments.
// key = (bits(v)<<32) | ~flat_idx. 8 LDS counters per block; plain global
// stores; no global atomics, no pre-zeroing (raw counts let K2 detect
// overflow -> fallback). Memory-bound: 86 MB read ~= 15 us.
__global__ __launch_bounds__(256) void stage_kernel(const float4* __restrict__ scores4,
                                                    unsigned* __restrict__ segCnt,
                                                    unsigned long long* __restrict__ segKeys) {
    __shared__ unsigned lcnt[NBKT];
    int b = blockIdx.x, sl = blockIdx.y, tid = threadIdx.x;
    if (tid < NBKT) lcnt[tid] = 0;
    __syncthreads();
    const float4* s = scores4 + (size_t)b * NCV4 + (size_t)sl * SLICE_V4;
    for (int i = tid; i < SLICE_V4; i += 256) {
        float4 v = s[i];
        float c[4] = {v.x, v.y, v.z, v.w};
        unsigned flat0 = ((unsigned)sl * SLICE_V4 + (unsigned)i) * 4u;
        #pragma unroll
        for (int kc = 0; kc < 4; ++kc) {
            float x = (c[kc] > 0.001f) ? c[kc] : 0.0f;
            if (x >= STAGE_THRESH) {
                int bin = (int)(x * 4096.0f);             // exact: x * 2^12
                bin = bin > (NBINS - 1) ? (NBINS - 1) : bin;
                int bkt = bin - 4088;                      // 0..7
                unsigned p = atomicAdd(&lcnt[bkt], 1u);
                if (p < (unsigned)SEGB)
                    segKeys[(((size_t)(b * NBKT + bkt)) * NSLICE + sl) * SEGB + p] =
                        ((unsigned long long)__float_as_uint(x) << 32) |
                        (unsigned long long)(0xFFFFFFFFu - (flat0 + kc));
            }
        }
    }
    __syncthreads();
    if (tid < NBKT) segCnt[(b * NBKT + tid) * NSLICE + sl] = lcnt[tid];
}

// ---------------------------------------------------------------------------
// K2: one WAVE per (batch,bucket) — 256 parallel blocks. Fast path: gather the
// bucket's 16 slice-segments with all loads in flight (4 lanes per segment),
// then RANK-AND-SCATTER: pos = bucket_base + #{greater keys in bucket}. Keys
// are unique (distinct idx low bits) so ranks are an exact permutation; this
// replaces the 36-pass bitonic's dependent LDS round-trips with ONE unrolled
// broadcast-compare pass (all reads independent). Invalid inputs: block (b,0)
// runs the exact histogram fallback single-wave (never on bench input).
__global__ __launch_bounds__(64) void select_kernel(
        const float4* __restrict__ scores4,
        const unsigned long long* __restrict__ segKeys,
        const unsigned* __restrict__ segCnt,
        const float4* __restrict__ boxes4,
        float* __restrict__ topScore,
        float4* __restrict__ topBox4,
        int* __restrict__ topCls) {
    __shared__ unsigned long long kbuf[CANDCAP];    // 32 KB (fast path uses 260)
    __shared__ unsigned scnt2[NBKT * NSLICE];       // all 128 segment counts
    __shared__ unsigned spref[NSLICE];              // own-bucket slice prefix
    __shared__ unsigned scnt;
    __shared__ int s_cut;
    int b = blockIdx.x, bkt = blockIdx.y, lane = threadIdx.x;

    // P0: load all 128 counts (2 coalesced loads/lane); every lane redundantly
    // computes bucket sums / validity / base from LDS broadcasts (lockstep).
    scnt2[lane]      = segCnt[b * NBKT * NSLICE + lane];
    scnt2[lane + 64] = segCnt[b * NBKT * NSLICE + lane + 64];
    __threadfence_block();
    unsigned M = 0, base = 0, n = 0; int valid = 1;
    #pragma unroll
    for (int t = 0; t < NBKT; ++t) {
        unsigned s2 = 0, mx = 0;
        #pragma unroll
        for (int sl = 0; sl < NSLICE; ++sl) {
            unsigned v = scnt2[t * NSLICE + sl];
            s2 += v; mx = v > mx ? v : mx;
        }
        if (mx > (unsigned)SEGB || s2 > (unsigned)BSORT) valid = 0;
        M += s2;
        if (t > bkt) base += s2;
        if (t == bkt) n = s2;
    }
    if (M < (unsigned)TOPK || M > (unsigned)CANDCAP) valid = 0;

    if (valid) {
        if (base >= (unsigned)TOPK || n == 0) return;
        // slice prefixes within own bucket
        if (lane < NSLICE) {
            unsigned acc = 0;
            for (int s2 = 0; s2 < lane; ++s2) acc += scnt2[bkt * NSLICE + s2];
            spref[lane] = acc;
        }
        __threadfence_block();
        // P1: gather — 16 segments concurrently, 4 lanes each (max load ILP)
        {
            int sl = lane & 15;
            int eo = lane >> 4;                      // 0..3
            unsigned cA = scnt2[bkt * NSLICE + sl];  // <= SEGB in valid path
            unsigned b0 = spref[sl];
            const unsigned long long* src =
                segKeys + (((size_t)(b * NBKT + bkt)) * NSLICE + sl) * SEGB;
            for (int e = eo; e < (int)cA; e += 4) kbuf[b0 + e] = src[e];
            if (lane < 4) kbuf[n + lane] = 0ull;     // pad for 4-wide rank loop
        }
        __threadfence_block();
        // P2: rank-and-scatter, 4 keys/lane, 4 independent reads per iter.
        int j0 = lane, j1 = lane + 64, j2 = lane + 128, j3 = lane + 192;
        unsigned long long k0 = (j0 < (int)n) ? kbuf[j0] : 0ull;
        unsigned long long k1 = (j1 < (int)n) ? kbuf[j1] : 0ull;
        unsigned long long k2 = (j2 < (int)n) ? kbuf[j2] : 0ull;
        unsigned long long k3 = (j3 < (int)n) ? kbuf[j3] : 0ull;
        unsigned r0 = 0, r1 = 0, r2 = 0, r3 = 0;
        for (unsigned i = 0; i < n; i += 4) {        // pad keys are 0: never >
            unsigned long long a = kbuf[i], b2 = kbuf[i + 1];
            unsigned long long c2 = kbuf[i + 2], d2 = kbuf[i + 3];
            r0 += (unsigned)(a > k0) + (unsigned)(b2 > k0) +
                  (unsigned)(c2 > k0) + (unsigned)(d2 > k0);
            r1 += (unsigned)(a > k1) + (unsigned)(b2 > k1) +
                  (unsigned)(c2 > k1) + (unsigned)(d2 > k1);
            r2 += (unsigned)(a > k2) + (unsigned)(b2 > k2) +
                  (unsigned)(c2 > k2) + (unsigned)(d2 > k2);
            r3 += (unsigned)(a > k3) + (unsigned)(b2 > k3) +
                  (unsigned)(c2 > k3) + (unsigned)(d2 > k3);
        }
        #pragma unroll
        for (int q = 0; q < 4; ++q) {
            int j = q == 0 ? j0 : q == 1 ? j1 : q == 2 ? j2 : j3;
            unsigned long long k = q == 0 ? k0 : q == 1 ? k1 : q == 2 ? k2 : k3;
            unsigned r = q == 0 ? r0 : q == 1 ? r1 : q == 2 ? r2 : r3;
            if (j < (int)n) {
                unsigned pos = base + r;
                if (pos < (unsigned)TOPK) {
                    float sc = __uint_as_float((unsigned)(k >> 32));
                    unsigned idx = 0xFFFFFFFFu - (unsigned)(k & 0xFFFFFFFFull);
                    if (idx >= (unsigned)NC) idx = 0;    // defensive
                    unsigned bi = idx / (unsigned)C_;
                    unsigned cl = idx - bi * (unsigned)C_;
                    topScore[b * TOPK + pos] = sc;
                    topBox4[b * TOPK + pos] = boxes4[(size_t)b * N_ + bi];
                    topCls[b * TOPK + pos] = (int)cl;
                }
            }
        }
        return;
    }

    // ---- exact fallback: only block (b, bkt=0); single wave, fences only.
    if (bkt != 0) return;
    unsigned* fh = (unsigned*)kbuf;      // aliases kbuf; dead before kbuf written
    for (int i2 = lane; i2 < NBINS; i2 += 64) fh[i2] = 0;
    if (lane == 0) scnt = 0;
    __threadfence_block();
    const float4* s = scores4 + (size_t)b * NCV4;
    for (int i2 = lane; i2 < NCV4; i2 += 64) {
        float4 v = s[i2];
        float c4[4] = {v.x, v.y, v.z, v.w};
        #pragma unroll
        for (int kc = 0; kc < 4; ++kc) {
            float x = (c4[kc] > 0.001f) ? c4[kc] : 0.0f;
            int bin = (int)(x * 4096.0f);
            bin = bin > (NBINS - 1) ? (NBINS - 1) : bin;
            atomicAdd(&fh[bin], 1u);
        }
    }
    __threadfence_block();
    if (lane == 0) {
        unsigned acc = 0; int cb = 0;
        for (int bin = NBINS - 1; bin >= 0; --bin) {
            acc += fh[bin];
            if (acc >= (unsigned)TOPK) { cb = bin; break; }
        }
        s_cut = cb;
    }
    __threadfence_block();               // lane0's fh reads done (lockstep)
    int cb = s_cut;
    for (int i2 = lane; i2 < NCV4; i2 += 64) {
        float4 v = s[i2];
        float c4[4] = {v.x, v.y, v.z, v.w};
        unsigned flat0 = (unsigned)i2 * 4u;
        #pragma unroll
        for (int kc = 0; kc < 4; ++kc) {
            float x = (c4[kc] > 0.001f) ? c4[kc] : 0.0f;
            int bin = (int)(x * 4096.0f);
            bin = bin > (NBINS - 1) ? (NBINS - 1) : bin;
            if (bin >= cb) {
                unsigned p = atomicAdd(&scnt, 1u);
                if (p < (unsigned)CANDCAP)
                    kbuf[p] = ((unsigned long long)__float_as_uint(x) << 32) |
                              (unsigned long long)(0xFFFFFFFFu - (flat0 + kc));
            }
        }
    }
    __threadfence_block();
    unsigned M2 = scnt; if (M2 > (unsigned)CANDCAP) M2 = CANDCAP;
    int S = (M2 <= 1024u) ? 1024 : (M2 <= 2048u ? 2048 : CANDCAP);
    for (int i2 = (int)M2 + lane; i2 < S; i2 += 64) kbuf[i2] = 0ull;
    __threadfence_block();
    for (int kk = 2; kk <= S; kk <<= 1) {
        for (int j = kk >> 1; j > 0; j >>= 1) {
            for (int t = lane; t < S; t += 64) {
                int l = t ^ j;
                if (l > t) {
                    unsigned long long a0 = kbuf[t], c0 = kbuf[l];
                    bool sw = ((t & kk) == 0) ? (a0 < c0) : (a0 > c0);
                    if (sw) { kbuf[t] = c0; kbuf[l] = a0; }
                }
            }
            __threadfence_block();
        }
    }
    for (int r = lane; r < TOPK; r += 64) {
        unsigned long long key = kbuf[r];
        float sc = __uint_as_float((unsigned)(key >> 32));
        unsigned idx = 0xFFFFFFFFu - (unsigned)(key & 0xFFFFFFFFull);
        if (idx >= (unsigned)NC) idx = 0;
        unsigned bi = idx / (unsigned)C_;
        unsigned cl = idx - bi * (unsigned)C_;
        topScore[b * TOPK + r] = sc;
        topBox4[b * TOPK + r] = boxes4[(size_t)b * N_ + bi];
        topCls[b * TOPK + r] = (int)cl;
    }
}

// ---------------------------------------------------------------------------
// K3: per-(batch,class) greedy NMS, one 64-thread block per (b,c) — 2560-way
// parallel; per-block serial chain is only ~13 greedy steps. Cross-class IoU
// is exactly 0 (offset gap 4096 >> max box 640), so per-class greedy NMS is
// exactly equivalent to the reference's global sequential loop. IoU replicated
// in f32 with __fmul_rn to block FMA contraction. (Round-0-proven kernel.)
#define CLS_CAP 256
__global__ __launch_bounds__(64) void nms_kernel(const float* __restrict__ topScore,
                                                 const float* __restrict__ topBox,
                                                 const int* __restrict__ topCls,
                                                 int* __restrict__ keep) {
    __shared__ unsigned short pos[CLS_CAP];
    __shared__ float by1[CLS_CAP], bx1[CLS_CAP], by2[CLS_CAP], bx2[CLS_CAP];
    __shared__ float barea[CLS_CAP];
    __shared__ unsigned char sup[CLS_CAP];
    int b = blockIdx.x;
    int c = blockIdx.y;
    int lane = threadIdx.x;
    const float* ts = topScore + b * TOPK;
    const int*   tc = topCls + b * TOPK;
    int*         kp = keep + b * TOPK;
    float off = (float)c * 4096.0f;         // exact
    int base = 0;
    for (int chunkS = 0; chunkS < TOPK; chunkS += 64) {
        int i = chunkS + lane;
        int cls = tc[i];
        float sc = ts[i];
        bool mine = (cls == c);
        bool listed = mine && (sc > 0.001f);
        if (mine) kp[i] = 0;                 // default; kept ones overwritten below
        unsigned long long mask = __ballot(listed);
        int rank = __popcll(mask & ((1ull << lane) - 1ull));
        if (listed) {
            int slot = base + rank;
            if (slot < CLS_CAP) {
                pos[slot] = (unsigned short)i;
                const float* tb = topBox + ((size_t)(b * TOPK + i)) * 4;
                float y1 = tb[0] + off, x1 = tb[1] + off;
                float y2 = tb[2] + off, x2 = tb[3] + off;
                by1[slot] = y1; bx1[slot] = x1; by2[slot] = y2; bx2[slot] = x2;
                barea[slot] = __fmul_rn((x2 - x1) + 1.0f, (y2 - y1) + 1.0f);
                sup[slot] = 0;
            }
        }
        base += __popcll(mask);
    }
    int m = base < CLS_CAP ? base : CLS_CAP;
    __syncthreads();
    int cur = 0;
    while (cur < m) {
        // invariant: slot `cur` is unsuppressed -> kept
        if (lane == 0) kp[pos[cur]] = 1;
        float cy1 = by1[cur], cx1 = bx1[cur], cy2 = by2[cur], cx2 = bx2[cur];
        float carea = barea[cur];
        for (int j = cur + 1 + lane; j < m; j += 64) {
            if (!sup[j]) {
                float yy1 = fmaxf(cy1, by1[j]), xx1 = fmaxf(cx1, bx1[j]);
                float yy2 = fminf(cy2, by2[j]), xx2 = fminf(cx2, bx2[j]);
                float w = fmaxf(0.0f, (xx2 - xx1) + 1.0f);
                float h = fmaxf(0.0f, (yy2 - yy1) + 1.0f);
                float inter = __fmul_rn(w, h);
                float denom = (carea + barea[j]) - inter;
                float iou = inter / denom;
                if (iou > 0.7f) sup[j] = 1;
            }
        }
        __syncthreads();
        int nxt = m;
        for (int j = cur + 1 + lane; j < m; j += 64)
            if (!sup[j]) { nxt = j; break; }
        for (int o = 32; o > 0; o >>= 1) {
            int other = __shfl_xor(nxt, o, 64);
            nxt = nxt < other ? nxt : other;
        }
        cur = nxt;
    }
}

// ---------------------------------------------------------------------------
// K4: stable top-300 of final_scores: kept positions in order, then suppressed
// positions in order (score-0 ties break by lower index). keep is 0/1, so the
// 1024-wide prefix sum is a ballot/popcount scan: per-wave prefix in-register,
// 16 wave totals combined from LDS — 2 barriers (was 20 with Hillis-Steele).
__global__ __launch_bounds__(1024) void finalize_kernel(const float* __restrict__ topScore,
                                                        const float* __restrict__ topBox,
                                                        const int* __restrict__ topCls,
                                                        const int* __restrict__ keep,
                                                        float* __restrict__ out) {
    __shared__ int wsum[16];
    __shared__ int sel[MAXDET];
    int b = blockIdx.x;
    int tid = threadIdx.x;
    int lane = tid & 63;
    int wave = tid >> 6;
    int kp = keep[b * TOPK + tid];
    unsigned long long m = __ballot(kp != 0);
    int wpre = __popcll(m & ((1ull << lane) - 1ull));
    if (lane == 0) wsum[wave] = __popcll(m);
    __syncthreads();
    int wbase = 0, nk = 0;
    #pragma unroll
    for (int t = 0; t < 16; ++t) {
        int v = wsum[t];
        if (t < wave) wbase += v;
        nk += v;
    }
    int kexcl = wbase + wpre;    // exclusive kept rank
    int sexcl = tid - kexcl;     // exclusive suppressed rank
    if (kp) {
        if (kexcl < MAXDET) sel[kexcl] = tid;
    } else {
        int slot = nk + sexcl;
        if (slot < MAXDET) sel[slot] = tid;
    }
    __syncthreads();
    if (tid < MAXDET) {
        int p = sel[tid];
        float sc = (tid < nk) ? topScore[b * TOPK + p] : 0.0f;
        const float4 tb = ((const float4*)topBox)[(size_t)b * TOPK + p];
        float* ob = out + ((size_t)b * MAXDET + tid) * 4;
        ob[0] = tb.x; ob[1] = tb.y; ob[2] = tb.z; ob[3] = tb.w;
        out[OUT_SCORES + b * MAXDET + tid] = sc;
        out[OUT_LABELS + b * MAXDET + tid] = (float)topCls[b * TOPK + p];
    }
    if (tid == 0) out[OUT_NVALID + b] = (float)(nk < MAXDET ? nk : MAXDET);
}

// ---------------------------------------------------------------------------
extern "C" void kernel_launch(void* const* d_in, const int* in_sizes, int n_in,
                              void* d_out, int out_size, void* d_ws, size_t ws_size,
                              hipStream_t stream) {
    const float* boxes  = (const float*)d_in[0];   // (32, 8400, 4)
    const float* scores = (const float*)d_in[1];   // (32, 8400, 80)
    float* out = (float*)d_out;
    char* ws = (char*)d_ws;

    unsigned long long* segKeys = (unsigned long long*)(ws + WS_SEGKEYS);
    unsigned* segCnt = (unsigned*)(ws + WS_SEGCNT);
    float* topScore = (float*)(ws + WS_TOPSCORE);
    float* topBox = (float*)(ws + WS_TOPBOX);
    int* topCls = (int*)(ws + WS_TOPCLS);
    int* keep = (int*)(ws + WS_KEEP);

    const float4* scores4 = (const float4*)scores;
    const float4* boxes4  = (const float4*)boxes;

    stage_kernel<<<dim3(B_, NSLICE), 256, 0, stream>>>(scores4, segCnt, segKeys);
    select_kernel<<<dim3(B_, NBKT), 64, 0, stream>>>(scores4, segKeys, segCnt, boxes4,
                                                     topScore, (float4*)topBox, topCls);
    nms_kernel<<<dim3(B_, C_), 64, 0, stream>>>(topScore, topBox, topCls, keep);
    finalize_kernel<<<B_, 1024, 0, stream>>>(topScore, topBox, topCls, keep, out);
}

// Round 3
// 173.986 us; speedup vs baseline: 1.2843x; 1.0326x over previous
//
#include <hip/hip_runtime.h>
#include <cstdint>
#include <cstddef>

// Problem constants (fixed by the reference)
#define B_      32
#define N_      8400
#define C_      80
#define NC      672000        // N_*C_
#define NCV4    168000        // NC/4
#define NBINS   4096
#define TOPK    1024
#define MAXDET  300
#define CANDCAP 4096
#define NSLICE  16
#define SLICE_V4 10500        // NCV4 / NSLICE
#define NBKT    8             // score bins 4088..4095 (all x in [0.998..1))
#define SEGB    64            // per-(batch,bucket,slice) cap (mean 10.25, 17 sigma)
#define BSORT   256           // per-bucket cap (mean 164, 7.2 sigma)

// Static stage threshold: score >= 4088/4096 = 0.998046875.
// Expected candidates/batch = 672000*8/4096 = 1312 (sd ~36). Bucket = bin-4088
// partitions candidates into 8 ORDER-DISJOINT groups (floor is monotone, float
// bits are monotone): buckets concatenated 7..0 == exact lax.top_k order
// (score desc, index asc via key low bits). Violating inputs take the exact
// in-kernel histogram fallback (never on bench input).
#define STAGE_THRESH 0.998046875f

// Workspace layout (bytes). Cross-kernel interface is COMPRESSED: class+valid
// packed to 1 byte/position (clsv), keep as 1 byte/position. topCls deleted.
#define WS_SEGKEYS  0           // 32*8*16*64*8 = 2097152
#define WS_SEGCNT   2097152     // 32*8*16*4    = 16384
#define WS_TOPSCORE 2113536     // 32*1024*4    = 131072
#define WS_TOPBOX   2244608     // 32*1024*16   = 524288
#define WS_CLSV     2768896     // 32*1024*1    = 32768   (0x80|class, 0 = invalid)
#define WS_KEEP     2801664     // 32*1024*1    = 32768

// Output layout (float32, concatenated): boxes[32][300][4], scores[32][300],
// labels[32][300], n_valid[32]
#define OUT_SCORES  38400
#define OUT_LABELS  48000
#define OUT_NVALID  57600

// ---------------------------------------------------------------------------
// K1: single-pass filter+stage into PRIVATE per-(batch,bucket,slice) segments.
// key = (bits(v)<<32) | ~flat_idx. 8 LDS counters per block; plain global
// stores; no global atomics, no pre-zeroing (raw counts let K2 detect
// overflow -> fallback). Memory-bound: 86 MB read ~= 15 us.
__global__ __launch_bounds__(256) void stage_kernel(const float4* __restrict__ scores4,
                                                    unsigned* __restrict__ segCnt,
                                                    unsigned long long* __restrict__ segKeys) {
    __shared__ unsigned lcnt[NBKT];
    int b = blockIdx.x, sl = blockIdx.y, tid = threadIdx.x;
    if (tid < NBKT) lcnt[tid] = 0;
    __syncthreads();
    const float4* s = scores4 + (size_t)b * NCV4 + (size_t)sl * SLICE_V4;
    for (int i = tid; i < SLICE_V4; i += 256) {
        float4 v = s[i];
        float c[4] = {v.x, v.y, v.z, v.w};
        unsigned flat0 = ((unsigned)sl * SLICE_V4 + (unsigned)i) * 4u;
        #pragma unroll
        for (int kc = 0; kc < 4; ++kc) {
            float x = (c[kc] > 0.001f) ? c[kc] : 0.0f;
            if (x >= STAGE_THRESH) {
                int bin = (int)(x * 4096.0f);             // exact: x * 2^12
                bin = bin > (NBINS - 1) ? (NBINS - 1) : bin;
                int bkt = bin - 4088;                      // 0..7
                unsigned p = atomicAdd(&lcnt[bkt], 1u);
                if (p < (unsigned)SEGB)
                    segKeys[(((size_t)(b * NBKT + bkt)) * NSLICE + sl) * SEGB + p] =
                        ((unsigned long long)__float_as_uint(x) << 32) |
                        (unsigned long long)(0xFFFFFFFFu - (flat0 + kc));
            }
        }
    }
    __syncthreads();
    if (tid < NBKT) segCnt[(b * NBKT + tid) * NSLICE + sl] = lcnt[tid];
}

// ---------------------------------------------------------------------------
// K2: one WAVE per (batch,bucket) — 256 parallel blocks. Fast path: gather the
// bucket's 16 slice-segments with all loads in flight, then RANK-AND-SCATTER:
// pos = bucket_base + #{greater keys in bucket}. Keys unique => exact
// permutation == lax.top_k order. Writes topScore/topBox + packed clsv byte;
// bkt-0 block also zeroes keep (1 KB, one uint4 store round). Invalid inputs:
// block (b,0) runs the exact histogram fallback (never on bench input).
__global__ __launch_bounds__(64) void select_kernel(
        const float4* __restrict__ scores4,
        const unsigned long long* __restrict__ segKeys,
        const unsigned* __restrict__ segCnt,
        const float4* __restrict__ boxes4,
        float* __restrict__ topScore,
        float4* __restrict__ topBox4,
        unsigned char* __restrict__ clsv,
        unsigned char* __restrict__ keepB) {
    __shared__ unsigned long long kbuf[CANDCAP];    // 32 KB (fast path uses 260)
    __shared__ unsigned scnt2[NBKT * NSLICE];       // all 128 segment counts
    __shared__ unsigned spref[NSLICE];              // own-bucket slice prefix
    __shared__ unsigned scnt;
    __shared__ int s_cut;
    int b = blockIdx.x, bkt = blockIdx.y, lane = threadIdx.x;

    // P0: load all 128 counts (2 coalesced loads/lane); every lane redundantly
    // computes bucket sums / validity / base from LDS broadcasts (lockstep).
    scnt2[lane]      = segCnt[b * NBKT * NSLICE + lane];
    scnt2[lane + 64] = segCnt[b * NBKT * NSLICE + lane + 64];
    __threadfence_block();
    unsigned M = 0, base = 0, n = 0; int valid = 1;
    #pragma unroll
    for (int t = 0; t < NBKT; ++t) {
        unsigned s2 = 0, mx = 0;
        #pragma unroll
        for (int sl = 0; sl < NSLICE; ++sl) {
            unsigned v = scnt2[t * NSLICE + sl];
            s2 += v; mx = v > mx ? v : mx;
        }
        if (mx > (unsigned)SEGB || s2 > (unsigned)BSORT) valid = 0;
        M += s2;
        if (t > bkt) base += s2;
        if (t == bkt) n = s2;
    }
    if (M < (unsigned)TOPK || M > (unsigned)CANDCAP) valid = 0;

    if (valid) {
        if (bkt == 0) {                              // zero keep BEFORE any return
            uint4 z; z.x = 0u; z.y = 0u; z.z = 0u; z.w = 0u;
            ((uint4*)(keepB + (size_t)b * TOPK))[lane] = z;
        }
        if (base >= (unsigned)TOPK || n == 0) return;
        // slice prefixes within own bucket
        if (lane < NSLICE) {
            unsigned acc = 0;
            for (int s2 = 0; s2 < lane; ++s2) acc += scnt2[bkt * NSLICE + s2];
            spref[lane] = acc;
        }
        __threadfence_block();
        // P1: gather — 16 segments concurrently, 4 lanes each (max load ILP)
        {
            int sl = lane & 15;
            int eo = lane >> 4;                      // 0..3
            unsigned cA = scnt2[bkt * NSLICE + sl];  // <= SEGB in valid path
            unsigned b0 = spref[sl];
            const unsigned long long* src =
                segKeys + (((size_t)(b * NBKT + bkt)) * NSLICE + sl) * SEGB;
            for (int e = eo; e < (int)cA; e += 4) kbuf[b0 + e] = src[e];
            if (lane < 4) kbuf[n + lane] = 0ull;     // pad for 4-wide rank loop
        }
        __threadfence_block();
        // P2: rank-and-scatter, 4 keys/lane, 4 independent reads per iter.
        int j0 = lane, j1 = lane + 64, j2 = lane + 128, j3 = lane + 192;
        unsigned long long k0 = (j0 < (int)n) ? kbuf[j0] : 0ull;
        unsigned long long k1 = (j1 < (int)n) ? kbuf[j1] : 0ull;
        unsigned long long k2 = (j2 < (int)n) ? kbuf[j2] : 0ull;
        unsigned long long k3 = (j3 < (int)n) ? kbuf[j3] : 0ull;
        unsigned r0 = 0, r1 = 0, r2 = 0, r3 = 0;
        for (unsigned i = 0; i < n; i += 4) {        // pad keys are 0: never >
            unsigned long long a = kbuf[i], b2 = kbuf[i + 1];
            unsigned long long c2 = kbuf[i + 2], d2 = kbuf[i + 3];
            r0 += (unsigned)(a > k0) + (unsigned)(b2 > k0) +
                  (unsigned)(c2 > k0) + (unsigned)(d2 > k0);
            r1 += (unsigned)(a > k1) + (unsigned)(b2 > k1) +
                  (unsigned)(c2 > k1) + (unsigned)(d2 > k1);
            r2 += (unsigned)(a > k2) + (unsigned)(b2 > k2) +
                  (unsigned)(c2 > k2) + (unsigned)(d2 > k2);
            r3 += (unsigned)(a > k3) + (unsigned)(b2 > k3) +
                  (unsigned)(c2 > k3) + (unsigned)(d2 > k3);
        }
        #pragma unroll
        for (int q = 0; q < 4; ++q) {
            int j = q == 0 ? j0 : q == 1 ? j1 : q == 2 ? j2 : j3;
            unsigned long long k = q == 0 ? k0 : q == 1 ? k1 : q == 2 ? k2 : k3;
            unsigned r = q == 0 ? r0 : q == 1 ? r1 : q == 2 ? r2 : r3;
            if (j < (int)n) {
                unsigned pos = base + r;
                if (pos < (unsigned)TOPK) {
                    float sc = __uint_as_float((unsigned)(k >> 32));
                    unsigned idx = 0xFFFFFFFFu - (unsigned)(k & 0xFFFFFFFFull);
                    if (idx >= (unsigned)NC) idx = 0;    // defensive
                    unsigned bi = idx / (unsigned)C_;
                    unsigned cl = idx - bi * (unsigned)C_;
                    topScore[b * TOPK + pos] = sc;
                    topBox4[b * TOPK + pos] = boxes4[(size_t)b * N_ + bi];
                    clsv[(size_t)b * TOPK + pos] = (unsigned char)(0x80u | cl);
                }
            }
        }
        return;
    }

    // ---- exact fallback: only block (b, bkt=0); single wave, fences only.
    if (bkt != 0) return;
    {
        uint4 z; z.x = 0u; z.y = 0u; z.z = 0u; z.w = 0u;
        ((uint4*)(keepB + (size_t)b * TOPK))[lane] = z;
    }
    unsigned* fh = (unsigned*)kbuf;      // aliases kbuf; dead before kbuf written
    for (int i2 = lane; i2 < NBINS; i2 += 64) fh[i2] = 0;
    if (lane == 0) scnt = 0;
    __threadfence_block();
    const float4* s = scores4 + (size_t)b * NCV4;
    for (int i2 = lane; i2 < NCV4; i2 += 64) {
        float4 v = s[i2];
        float c4[4] = {v.x, v.y, v.z, v.w};
        #pragma unroll
        for (int kc = 0; kc < 4; ++kc) {
            float x = (c4[kc] > 0.001f) ? c4[kc] : 0.0f;
            int bin = (int)(x * 4096.0f);
            bin = bin > (NBINS - 1) ? (NBINS - 1) : bin;
            atomicAdd(&fh[bin], 1u);
        }
    }
    __threadfence_block();
    if (lane == 0) {
        unsigned acc = 0; int cb = 0;
        for (int bin = NBINS - 1; bin >= 0; --bin) {
            acc += fh[bin];
            if (acc >= (unsigned)TOPK) { cb = bin; break; }
        }
        s_cut = cb;
    }
    __threadfence_block();               // lane0's fh reads done (lockstep)
    int cb = s_cut;
    for (int i2 = lane; i2 < NCV4; i2 += 64) {
        float4 v = s[i2];
        float c4[4] = {v.x, v.y, v.z, v.w};
        unsigned flat0 = (unsigned)i2 * 4u;
        #pragma unroll
        for (int kc = 0; kc < 4; ++kc) {
            float x = (c4[kc] > 0.001f) ? c4[kc] : 0.0f;
            int bin = (int)(x * 4096.0f);
            bin = bin > (NBINS - 1) ? (NBINS - 1) : bin;
            if (bin >= cb) {
                unsigned p = atomicAdd(&scnt, 1u);
                if (p < (unsigned)CANDCAP)
                    kbuf[p] = ((unsigned long long)__float_as_uint(x) << 32) |
                              (unsigned long long)(0xFFFFFFFFu - (flat0 + kc));
            }
        }
    }
    __threadfence_block();
    unsigned M2 = scnt; if (M2 > (unsigned)CANDCAP) M2 = CANDCAP;
    int S = (M2 <= 1024u) ? 1024 : (M2 <= 2048u ? 2048 : CANDCAP);
    for (int i2 = (int)M2 + lane; i2 < S; i2 += 64) kbuf[i2] = 0ull;
    __threadfence_block();
    for (int kk = 2; kk <= S; kk <<= 1) {
        for (int j = kk >> 1; j > 0; j >>= 1) {
            for (int t = lane; t < S; t += 64) {
                int l = t ^ j;
                if (l > t) {
                    unsigned long long a0 = kbuf[t], c0 = kbuf[l];
                    bool sw = ((t & kk) == 0) ? (a0 < c0) : (a0 > c0);
                    if (sw) { kbuf[t] = c0; kbuf[l] = a0; }
                }
            }
            __threadfence_block();
        }
    }
    for (int r = lane; r < TOPK; r += 64) {
        unsigned long long key = kbuf[r];
        float sc = __uint_as_float((unsigned)(key >> 32));
        unsigned idx = 0xFFFFFFFFu - (unsigned)(key & 0xFFFFFFFFull);
        if (idx >= (unsigned)NC) idx = 0;
        unsigned bi = idx / (unsigned)C_;
        unsigned cl = idx - bi * (unsigned)C_;
        topScore[b * TOPK + r] = sc;
        topBox4[b * TOPK + r] = boxes4[(size_t)b * N_ + bi];
        clsv[(size_t)b * TOPK + r] =
            (unsigned char)((sc > 0.001f ? 0x80u : 0u) | cl);
    }
}

// ---------------------------------------------------------------------------
// K3: per-(batch,class) greedy NMS, one 64-thread block per (b,c) — 2560-way
// parallel. Extraction is ONE coalesced 16 B/lane load of the packed class
// map (byte == 0x80|c <=> listed), per-lane popcount + 6-step shfl_up wave
// prefix, <=16-iter unrolled local place — replaces 16 serial ballot rounds
// of dependent global loads (the round-2 latency pig). Cross-class IoU is
// exactly 0 (offset gap 4096 >> max box 640) => per-class greedy == the
// reference's global sequential loop. IoU in f32 with __fmul_rn (no FMA).
#define CLS_CAP 256
__global__ __launch_bounds__(64) void nms_kernel(const unsigned char* __restrict__ clsv,
                                                 const float4* __restrict__ topBox4,
                                                 unsigned char* __restrict__ keepB) {
    __shared__ unsigned short spos[CLS_CAP];
    __shared__ float by1[CLS_CAP], bx1[CLS_CAP], by2[CLS_CAP], bx2[CLS_CAP];
    __shared__ float barea[CLS_CAP];
    __shared__ unsigned char sup[CLS_CAP];
    int b = blockIdx.x;
    int c = blockIdx.y;
    int lane = threadIdx.x;
    unsigned char* kp = keepB + (size_t)b * TOPK;

    // whole batch's class map: 16 consecutive bytes per lane, in registers
    uint4 w = ((const uint4*)(clsv + (size_t)b * TOPK))[lane];
    unsigned target = 0x80u | (unsigned)c;
    unsigned mmask = 0; int cnt = 0;
    #pragma unroll
    for (int t = 0; t < 16; ++t) {
        unsigned d = (t < 4) ? w.x : (t < 8) ? w.y : (t < 12) ? w.z : w.w;
        unsigned v = (d >> ((t & 3) * 8)) & 0xffu;
        if (v == target) { mmask |= (1u << t); ++cnt; }
    }
    // inclusive wave prefix over per-lane counts
    int x = cnt;
    #pragma unroll
    for (int o = 1; o < 64; o <<= 1) {
        int y = __shfl_up(x, o, 64);
        if (lane >= o) x += y;
    }
    int pre = x - cnt;
    int m = __shfl(x, 63, 64);
    // place own candidates: ascending (lane, t) == ascending pos == score desc
    int slot = pre;
    #pragma unroll
    for (int t = 0; t < 16; ++t) {
        if ((mmask >> t) & 1u) {
            if (slot < CLS_CAP) spos[slot] = (unsigned short)(lane * 16 + t);
            ++slot;
        }
    }
    int m2 = m < CLS_CAP ? m : CLS_CAP;
    __threadfence_block();
    // per-slot box setup (one random 16 B load per candidate, lane-parallel)
    float off = (float)c * 4096.0f;         // exact
    for (int j = lane; j < m2; j += 64) {
        int p = spos[j];
        float4 tb = topBox4[(size_t)b * TOPK + p];
        float y1 = tb.x + off, x1 = tb.y + off;
        float y2 = tb.z + off, x2 = tb.w + off;
        by1[j] = y1; bx1[j] = x1; by2[j] = y2; bx2[j] = x2;
        barea[j] = __fmul_rn((x2 - x1) + 1.0f, (y2 - y1) + 1.0f);
        sup[j] = 0;
    }
    __threadfence_block();
    int cur = 0;
    while (cur < m2) {
        // invariant: slot `cur` is unsuppressed -> kept
        if (lane == 0) kp[spos[cur]] = 1;
        float cy1 = by1[cur], cx1 = bx1[cur], cy2 = by2[cur], cx2 = bx2[cur];
        float carea = barea[cur];
        for (int j = cur + 1 + lane; j < m2; j += 64) {
            if (!sup[j]) {
                float yy1 = fmaxf(cy1, by1[j]), xx1 = fmaxf(cx1, bx1[j]);
                float yy2 = fminf(cy2, by2[j]), xx2 = fminf(cx2, bx2[j]);
                float w2 = fmaxf(0.0f, (xx2 - xx1) + 1.0f);
                float h2 = fmaxf(0.0f, (yy2 - yy1) + 1.0f);
                float inter = __fmul_rn(w2, h2);
                float denom = (carea + barea[j]) - inter;
                float iou = inter / denom;
                if (iou > 0.7f) sup[j] = 1;
            }
        }
        __threadfence_block();
        int nxt = m2;
        for (int j = cur + 1 + lane; j < m2; j += 64)
            if (!sup[j]) { nxt = j; break; }
        for (int o = 32; o > 0; o >>= 1) {
            int other = __shfl_xor(nxt, o, 64);
            nxt = nxt < other ? nxt : other;
        }
        cur = nxt;
    }
}

// ---------------------------------------------------------------------------
// K4: stable top-300 of final_scores: kept positions in order, then suppressed
// positions in order (score-0 ties break by lower index). keep is 0/1 uchar:
// ballot/popcount scan — 2 barriers. Labels derived from packed clsv.
__global__ __launch_bounds__(1024) void finalize_kernel(const float* __restrict__ topScore,
                                                        const float4* __restrict__ topBox4,
                                                        const unsigned char* __restrict__ clsv,
                                                        const unsigned char* __restrict__ keepB,
                                                        float* __restrict__ out) {
    __shared__ int wsum[16];
    __shared__ int sel[MAXDET];
    int b = blockIdx.x;
    int tid = threadIdx.x;
    int lane = tid & 63;
    int wave = tid >> 6;
    int kp = keepB[(size_t)b * TOPK + tid];
    unsigned long long mb = __ballot(kp != 0);
    int wpre = __popcll(mb & ((1ull << lane) - 1ull));
    if (lane == 0) wsum[wave] = __popcll(mb);
    __syncthreads();
    int wbase = 0, nk = 0;
    #pragma unroll
    for (int t = 0; t < 16; ++t) {
        int v = wsum[t];
        if (t < wave) wbase += v;
        nk += v;
    }
    int kexcl = wbase + wpre;    // exclusive kept rank
    int sexcl = tid - kexcl;     // exclusive suppressed rank
    if (kp) {
        if (kexcl < MAXDET) sel[kexcl] = tid;
    } else {
        int slot = nk + sexcl;
        if (slot < MAXDET) sel[slot] = tid;
    }
    __syncthreads();
    if (tid < MAXDET) {
        int p = sel[tid];
        float sc = (tid < nk) ? topScore[b * TOPK + p] : 0.0f;
        float4 tb = topBox4[(size_t)b * TOPK + p];
        float* ob = out + ((size_t)b * MAXDET + tid) * 4;
        ob[0] = tb.x; ob[1] = tb.y; ob[2] = tb.z; ob[3] = tb.w;
        out[OUT_SCORES + b * MAXDET + tid] = sc;
        out[OUT_LABELS + b * MAXDET + tid] =
            (float)(clsv[(size_t)b * TOPK + p] & 0x7f);
    }
    if (tid == 0) out[OUT_NVALID + b] = (float)(nk < MAXDET ? nk : MAXDET);
}

// ---------------------------------------------------------------------------
extern "C" void kernel_launch(void* const* d_in, const int* in_sizes, int n_in,
                              void* d_out, int out_size, void* d_ws, size_t ws_size,
                              hipStream_t stream) {
    const float* boxes  = (const float*)d_in[0];   // (32, 8400, 4)
    const float* scores = (const float*)d_in[1];   // (32, 8400, 80)
    float* out = (float*)d_out;
    char* ws = (char*)d_ws;

    unsigned long long* segKeys = (unsigned long long*)(ws + WS_SEGKEYS);
    unsigned* segCnt = (unsigned*)(ws + WS_SEGCNT);
    float* topScore = (float*)(ws + WS_TOPSCORE);
    float4* topBox4 = (float4*)(ws + WS_TOPBOX);
    unsigned char* clsv = (unsigned char*)(ws + WS_CLSV);
    unsigned char* keepB = (unsigned char*)(ws + WS_KEEP);

    const float4* scores4 = (const float4*)scores;
    const float4* boxes4  = (const float4*)boxes;

    stage_kernel<<<dim3(B_, NSLICE), 256, 0, stream>>>(scores4, segCnt, segKeys);
    select_kernel<<<dim3(B_, NBKT), 64, 0, stream>>>(scores4, segKeys, segCnt, boxes4,
                                                     topScore, topBox4, clsv, keepB);
    nms_kernel<<<dim3(B_, C_), 64, 0, stream>>>(clsv, topBox4, keepB);
    finalize_kernel<<<B_, 1024, 0, stream>>>(topScore, topBox4, clsv, keepB, out);
}